// Round 4
// baseline (177.422 us; speedup 1.0000x reference)
//
#include <hip/hip_runtime.h>

#define CCH 32
#define BCH 6
#define HH  180
#define WW  320
#define NN  (HH*WW)          // 57600
#define BATCH 32
#define TI  6                 // i0 = 0,32,...,160 (160 partial: 20 rows)
#define TJ  10                // j0 = 0,32,...,288
#define TILES (TI*TJ)         // 60

typedef float f32x2 __attribute__((ext_vector_type(2)));
typedef float f32x4 __attribute__((ext_vector_type(4)));

// Each block: one 32x32 z-aligned tile, 256 threads in Morton (quad) order.
// Thread t owns one aligned 2x2 quad = walk ranks [n_q, n_q+4), n_q % 4 == 0.
__global__ __launch_bounds__(256, 8) void fused_flatten_deflatten(
    const float* __restrict__ latent,    // (B, C, N)
    const float* __restrict__ w_flat,    // (BCH, C)
    const float* __restrict__ b_flat,    // (BCH,)
    const float* __restrict__ w_deflat,  // (C, BCH)
    const float* __restrict__ b_deflat,  // (C,)
    const float* __restrict__ se,        // (1, C, N)
    const int*   __restrict__ unwalk,    // (N,)
    float* __restrict__ recon,           // (B, C, N)
    float* __restrict__ flat_out)        // (B, BCH, N)
{
    __shared__ float s_wf[BCH*CCH];   // [o][c]
    __shared__ float s_wd[CCH*BCH];   // [c][o]
    __shared__ float s_bf[BCH];
    __shared__ float s_bd[CCH];
    __shared__ int   s_nbase;

    const int t  = threadIdx.x;
    const int bx = blockIdx.x;
    const int b  = bx / TILES;
    const int r  = bx % TILES;
    const int i0 = (r / TJ) * 32;
    const int j0 = (r % TJ) * 32;

    if (t < BCH*CCH) { s_wf[t] = w_flat[t]; s_wd[t] = w_deflat[t]; }
    if (t < BCH)     s_bf[t] = b_flat[t];
    if (t < CCH)     s_bd[t] = b_deflat[t];
    if (t == 0)      s_nbase = unwalk[i0*WW + j0];
    __syncthreads();

    // Quad-index Morton decode: t bits lsb->msb = j1,i1,j2,i2,j3,i3,j4,i4
    const int li = (((t>>1)&1)<<1) | (((t>>3)&1)<<2) | (((t>>5)&1)<<3) | (((t>>7)&1)<<4);
    const int lj = (((t>>0)&1)<<1) | (((t>>2)&1)<<2) | (((t>>4)&1)<<3) | (((t>>6)&1)<<4);
    const int i  = i0 + li;           // even row (quad top)
    const int j  = j0 + lj;           // even col
    if (i + 1 >= HH) return;          // bottom partial strip only

    const bool full = (i0 <= 128);    // full 32x32 tile -> contiguous walk range
    const int n_q = full ? (s_nbase + 4*t) : unwalk[i*WW + j];

    const float* latb   = latent + (size_t)b * (CCH*NN) + i*WW + j;
    float*       reconb = recon  + (size_t)b * (CCH*NN) + i*WW + j;

    // ---- pass 1: flat = W_f @ latent + b_f  (acc[o][k], k = walk order in quad)
    float acc[BCH][4];
    #pragma unroll
    for (int o = 0; o < BCH; ++o) {
        const float bo = s_bf[o];
        acc[o][0] = bo; acc[o][1] = bo; acc[o][2] = bo; acc[o][3] = bo;
    }

    #pragma unroll 8
    for (int c = 0; c < CCH; ++c) {
        const f32x2 xt = __builtin_nontemporal_load(
            reinterpret_cast<const f32x2*>(latb + (size_t)c*NN));
        const f32x2 xb = __builtin_nontemporal_load(
            reinterpret_cast<const f32x2*>(latb + (size_t)c*NN + WW));
        #pragma unroll
        for (int o = 0; o < BCH; ++o) {
            const float w = s_wf[o*CCH + c];
            acc[o][0] += w*xt.x; acc[o][1] += w*xt.y;
            acc[o][2] += w*xb.x; acc[o][3] += w*xb.y;
        }
    }

    // ---- flat store: walk order within quad = (i,j),(i,j+1),(i+1,j),(i+1,j+1)
    float* fb = flat_out + (size_t)b * (BCH*NN) + n_q;
    #pragma unroll
    for (int o = 0; o < BCH; ++o) {
        f32x4 v; v.x = acc[o][0]; v.y = acc[o][1]; v.z = acc[o][2]; v.w = acc[o][3];
        __builtin_nontemporal_store(v, reinterpret_cast<f32x4*>(fb + (size_t)o * NN));
    }

    // ---- pass 2: recon = W_d @ flat + b_d + se[:, n]
    const float* sen = se + n_q;
    #pragma unroll 8
    for (int c = 0; c < CCH; ++c) {
        const f32x4 s4 = *reinterpret_cast<const f32x4*>(sen + (size_t)c*NN);
        const float bd = s_bd[c];
        float y0 = bd + s4.x, y1 = bd + s4.y;   // top row (j, j+1)
        float y2 = bd + s4.z, y3 = bd + s4.w;   // bottom row
        #pragma unroll
        for (int o = 0; o < BCH; ++o) {
            const float w = s_wd[c*BCH + o];
            y0 += w*acc[o][0]; y1 += w*acc[o][1];
            y2 += w*acc[o][2]; y3 += w*acc[o][3];
        }
        f32x2 rt; rt.x = y0; rt.y = y1;
        f32x2 rb; rb.x = y2; rb.y = y3;
        __builtin_nontemporal_store(rt, reinterpret_cast<f32x2*>(reconb + (size_t)c*NN));
        __builtin_nontemporal_store(rb, reinterpret_cast<f32x2*>(reconb + (size_t)c*NN + WW));
    }
}

extern "C" void kernel_launch(void* const* d_in, const int* in_sizes, int n_in,
                              void* d_out, int out_size, void* d_ws, size_t ws_size,
                              hipStream_t stream) {
    const float* latent   = (const float*)d_in[0];
    const float* w_flat   = (const float*)d_in[1];
    const float* b_flat   = (const float*)d_in[2];
    const float* w_deflat = (const float*)d_in[3];
    const float* b_deflat = (const float*)d_in[4];
    const float* se       = (const float*)d_in[5];
    const int*   unwalk   = (const int*)d_in[7];   // d_in[6] = walk_idx (unused)

    float* recon = (float*)d_out;
    float* flat  = (float*)d_out + (size_t)BATCH * CCH * NN;

    dim3 grid(BATCH * TILES);   // 32 * 60 = 1920 blocks
    dim3 block(256);
    fused_flatten_deflatten<<<grid, block, 0, stream>>>(
        latent, w_flat, b_flat, w_deflat, b_deflat, se, unwalk, recon, flat);
}

// Round 5
// 131.690 us; speedup vs baseline: 1.3473x; 1.3473x over previous
//
#include <hip/hip_runtime.h>

#define CCH 32
#define BCH 6
#define HH  180
#define WW  320
#define NN  (HH*WW)             // 57600
#define BATCH 32
#define RPC 4                    // rows per chunk
#define CHUNKS (HH/RPC)          // 45
#define THREADS 320              // 5 waves; 4 px per thread (1280 px per chunk)

typedef float f32x2 __attribute__((ext_vector_type(2)));
typedef float f32x4 __attribute__((ext_vector_type(4)));

// ---- kernel A: se_raster[c][p] = se[c][unwalk[p]]  (7.4 MB, L2/L3-resident)
__global__ __launch_bounds__(256) void permute_se(
    const float* __restrict__ se, const int* __restrict__ unwalk,
    float* __restrict__ se_r)
{
    const int p = blockIdx.x * 256 + threadIdx.x;   // 225 * 256 = 57600 exact
    const int n = unwalk[p];
    #pragma unroll 8
    for (int c = 0; c < CCH; ++c)
        se_r[(size_t)c * NN + p] = se[(size_t)c * NN + n];
}

// ---- main kernel: 1D raster chunks (5 KB contiguous per c-plane per block)
template<int SE_RASTER>
__global__ __launch_bounds__(THREADS) void fused_flatten_deflatten(
    const float* __restrict__ latent,    // (B, C, N)
    const float* __restrict__ w_flat,    // (BCH, C)
    const float* __restrict__ b_flat,    // (BCH,)
    const float* __restrict__ w_deflat,  // (C, BCH)
    const float* __restrict__ b_deflat,  // (C,)
    const float* __restrict__ se,        // se_raster (ws) if SE_RASTER else se
    const int*   __restrict__ unwalk,    // (N,)
    float* __restrict__ recon,           // (B, C, N)
    float* __restrict__ flat_out)        // (B, BCH, N)
{
    __shared__ float s_wf[BCH*CCH];   // [o][c]
    __shared__ float s_wd[CCH*BCH];   // [c][o]
    __shared__ float s_bf[BCH];
    __shared__ float s_bd[CCH];

    const int t  = threadIdx.x;
    const int bx = blockIdx.x;
    const int r  = bx >> 5;            // chunk 0..44  (consecutive blocks share r)
    const int b  = bx & 31;            // batch

    if (t < BCH*CCH) { s_wf[t] = w_flat[t]; s_wd[t] = w_deflat[t]; }
    if (t < BCH)     s_bf[t] = b_flat[t];
    if (t < CCH)     s_bd[t] = b_deflat[t];
    __syncthreads();

    const int i  = RPC*r + t/80;       // row
    const int j  = 4*(t%80);           // col (multiple of 4)
    const int p  = i*WW + j;           // raster px of strip start (16B aligned)

    // walk ranks of the 1x4 strip: {n2, n2+1, n2+4, n2+5}
    const int nb = unwalk[(i & ~1)*WW + j];     // 2x4-block base rank (mult of 8)
    const int n2 = nb + 2*(i & 1);

    const float* latb   = latent + (size_t)b * (CCH*NN) + p;
    float*       reconb = recon  + (size_t)b * (CCH*NN) + p;

    // ---- pass 1: flat = W_f @ latent + b_f   (k = strip col 0..3)
    float acc[BCH][4];
    #pragma unroll
    for (int o = 0; o < BCH; ++o) {
        const float bo = s_bf[o];
        acc[o][0] = bo; acc[o][1] = bo; acc[o][2] = bo; acc[o][3] = bo;
    }

    #pragma unroll 8
    for (int c = 0; c < CCH; ++c) {
        const f32x4 x = __builtin_nontemporal_load(
            reinterpret_cast<const f32x4*>(latb + (size_t)c*NN));
        #pragma unroll
        for (int o = 0; o < BCH; ++o) {
            const float w = s_wf[o*CCH + c];
            acc[o][0] += w*x.x; acc[o][1] += w*x.y;
            acc[o][2] += w*x.z; acc[o][3] += w*x.w;
        }
    }

    // ---- flat stores: ranks n2,n2+1 (cols 0,1) and n2+4,n2+5 (cols 2,3)
    float* fb = flat_out + (size_t)b * (BCH*NN) + n2;
    #pragma unroll
    for (int o = 0; o < BCH; ++o) {
        f32x2 lo; lo.x = acc[o][0]; lo.y = acc[o][1];
        f32x2 hi; hi.x = acc[o][2]; hi.y = acc[o][3];
        *reinterpret_cast<f32x2*>(fb + (size_t)o*NN)     = lo;
        *reinterpret_cast<f32x2*>(fb + (size_t)o*NN + 4) = hi;
    }

    // ---- pass 2: recon = W_d @ flat + b_d + se
    #pragma unroll 8
    for (int c = 0; c < CCH; ++c) {
        float s0, s1, s2, s3;
        if (SE_RASTER) {
            const f32x4 s4 = *reinterpret_cast<const f32x4*>(se + (size_t)c*NN + p);
            s0 = s4.x; s1 = s4.y; s2 = s4.z; s3 = s4.w;
        } else {
            const f32x2 a = *reinterpret_cast<const f32x2*>(se + (size_t)c*NN + n2);
            const f32x2 bq = *reinterpret_cast<const f32x2*>(se + (size_t)c*NN + n2 + 4);
            s0 = a.x; s1 = a.y; s2 = bq.x; s3 = bq.y;
        }
        const float bd = s_bd[c];
        float y0 = bd + s0, y1 = bd + s1, y2 = bd + s2, y3 = bd + s3;
        #pragma unroll
        for (int o = 0; o < BCH; ++o) {
            const float w = s_wd[c*BCH + o];
            y0 += w*acc[o][0]; y1 += w*acc[o][1];
            y2 += w*acc[o][2]; y3 += w*acc[o][3];
        }
        f32x4 yv; yv.x = y0; yv.y = y1; yv.z = y2; yv.w = y3;
        *reinterpret_cast<f32x4*>(reconb + (size_t)c*NN) = yv;
    }
}

extern "C" void kernel_launch(void* const* d_in, const int* in_sizes, int n_in,
                              void* d_out, int out_size, void* d_ws, size_t ws_size,
                              hipStream_t stream) {
    const float* latent   = (const float*)d_in[0];
    const float* w_flat   = (const float*)d_in[1];
    const float* b_flat   = (const float*)d_in[2];
    const float* w_deflat = (const float*)d_in[3];
    const float* b_deflat = (const float*)d_in[4];
    const float* se       = (const float*)d_in[5];
    const int*   unwalk   = (const int*)d_in[7];   // d_in[6] = walk_idx (unused)

    float* recon = (float*)d_out;
    float* flat  = (float*)d_out + (size_t)BATCH * CCH * NN;

    const size_t se_bytes = (size_t)CCH * NN * sizeof(float);
    dim3 grid(CHUNKS * BATCH);       // 45 * 32 = 1440 blocks
    dim3 block(THREADS);

    if (ws_size >= se_bytes) {
        float* se_r = (float*)d_ws;
        permute_se<<<dim3(NN/256), dim3(256), 0, stream>>>(se, unwalk, se_r);
        fused_flatten_deflatten<1><<<grid, block, 0, stream>>>(
            latent, w_flat, b_flat, w_deflat, b_deflat, se_r, unwalk, recon, flat);
    } else {
        fused_flatten_deflatten<0><<<grid, block, 0, stream>>>(
            latent, w_flat, b_flat, w_deflat, b_deflat, se, unwalk, recon, flat);
    }
}